// Round 2
// baseline (73.921 us; speedup 1.0000x reference)
//
#include <hip/hip_runtime.h>
#include <hip/hip_bf16.h>
#include <math.h>

#define NROW 4096
#define DIM  512
#define TINV 10.0f
#define EPSN 1e-8f
#define BM 128
#define BN 128
#define BK 64

typedef __bf16 bf16x8 __attribute__((ext_vector_type(8)));
typedef float  f32x4  __attribute__((ext_vector_type(4)));

__device__ __forceinline__ void gload_lds16(const void* g, void* l) {
    __builtin_amdgcn_global_load_lds(
        (const __attribute__((address_space(1))) unsigned int*)g,
        (__attribute__((address_space(3))) unsigned int*)l,
        16, 0, 0);
}

// Kernel 1: row-normalize fp32 -> bf16. One wave per row, 8 elems/lane.
__global__ __launch_bounds__(256) void knorm(const float* __restrict__ feat,
                                             unsigned short* __restrict__ fb) {
    const int row  = blockIdx.x * 4 + (threadIdx.x >> 6);
    const int lane = threadIdx.x & 63;
    const float* rp = feat + (size_t)row * DIM + lane * 8;
    float4 v0 = *(const float4*)rp;
    float4 v1 = *(const float4*)(rp + 4);
    float ss = v0.x*v0.x + v0.y*v0.y + v0.z*v0.z + v0.w*v0.w
             + v1.x*v1.x + v1.y*v1.y + v1.z*v1.z + v1.w*v1.w;
    #pragma unroll
    for (int m = 1; m < 64; m <<= 1) ss += __shfl_xor(ss, m);
    const float inv = 1.0f / fmaxf(sqrtf(ss), EPSN);
    float vals[8] = {v0.x, v0.y, v0.z, v0.w, v1.x, v1.y, v1.z, v1.w};
    union { __hip_bfloat16 h[8]; int4 bits; } u;
    #pragma unroll
    for (int k = 0; k < 8; k++) u.h[k] = __float2bfloat16(vals[k] * inv);
    *(int4*)(fb + (size_t)row * DIM + lane * 8) = u.bits;
}

// Kernel 2: per-row target = first j != i with labels[j]==labels[i]
// (matches argmax of the positive mask in the diagonal-dropped layout).
// Also zeroes rowsum (runs before ksim on the same stream).
__global__ __launch_bounds__(256) void ktarget(const int* __restrict__ labels,
                                               int* __restrict__ target,
                                               float* __restrict__ rowsum) {
    __shared__ int firstS[16], secondS[16];
    const int t = threadIdx.x;
    if (t < 16) { firstS[t] = NROW; secondS[t] = NROW; }
    for (int i = t; i < NROW; i += 256) rowsum[i] = 0.0f;
    __syncthreads();
    for (int i = t; i < NROW; i += 256) atomicMin(&firstS[labels[i]], i);
    __syncthreads();
    for (int i = t; i < NROW; i += 256) {
        const int c = labels[i];
        if (i != firstS[c]) atomicMin(&secondS[c], i);
    }
    __syncthreads();
    for (int i = t; i < NROW; i += 256) {
        const int c = labels[i];
        int tg = (firstS[c] == i) ? secondS[c] : firstS[c];
        if (tg >= NROW) tg = (i == 0) ? 1 : 0;  // no-positive: first dropped column
        target[i] = tg;
    }
}

// Kernel 3: fused sim tile (bf16 MFMA) + exp + partial row sums + target capture.
// 128x128 tile per 256-thread block; 4 waves in 2x2, each owning 64x64 (4x4 frags).
__global__ __launch_bounds__(256) void ksim(const unsigned short* __restrict__ fb,
                                            const int* __restrict__ target,
                                            float* __restrict__ rowsum,
                                            float* __restrict__ tlog) {
    __shared__ __align__(16) unsigned short As[BM * BK];
    __shared__ __align__(16) unsigned short Bs[BN * BK];
    const int brow = blockIdx.y * BM;
    const int bcol = blockIdx.x * BN;
    const int tid  = threadIdx.x;
    const int wid  = tid >> 6;
    const int lane = tid & 63;
    const int wm = wid >> 1, wn = wid & 1;

    f32x4 acc[4][4];
    #pragma unroll
    for (int m = 0; m < 4; m++)
        #pragma unroll
        for (int n = 0; n < 4; n++)
            #pragma unroll
            for (int q = 0; q < 4; q++) acc[m][n][q] = 0.0f;

    const int r8  = lane >> 3;  // row within an 8-row group
    const int c16 = lane & 7;   // 16B chunk within a 128B row

    for (int kb = 0; kb < DIM; kb += BK) {
        // Stage A(128x64) and B(128x64) bf16 tiles; wave w covers rows [w*32, w*32+32).
        const unsigned short* gA = fb + (size_t)(brow + wid * 32 + r8) * DIM + kb + c16 * 8;
        const unsigned short* gB = fb + (size_t)(bcol + wid * 32 + r8) * DIM + kb + c16 * 8;
        unsigned short* lA = As + (wid * 32) * BK;
        unsigned short* lB = Bs + (wid * 32) * BK;
        #pragma unroll
        for (int q = 0; q < 4; q++) {
            gload_lds16(gA + (size_t)q * 8 * DIM, lA + q * 8 * BK);
            gload_lds16(gB + (size_t)q * 8 * DIM, lB + q * 8 * BK);
        }
        __syncthreads();

        const int ro = lane & 15;
        #pragma unroll
        for (int kk = 0; kk < 2; kk++) {
            const int ko = kk * 32 + (lane >> 4) * 8;
            bf16x8 a[4], b[4];
            #pragma unroll
            for (int m = 0; m < 4; m++)
                a[m] = *(const bf16x8*)(As + (wm * 64 + m * 16 + ro) * BK + ko);
            #pragma unroll
            for (int n = 0; n < 4; n++)
                b[n] = *(const bf16x8*)(Bs + (wn * 64 + n * 16 + ro) * BK + ko);
            #pragma unroll
            for (int m = 0; m < 4; m++)
                #pragma unroll
                for (int n = 0; n < 4; n++)
                    acc[m][n] = __builtin_amdgcn_mfma_f32_16x16x32_bf16(a[m], b[n], acc[m][n], 0, 0, 0);
        }
        __syncthreads();
    }

    // Epilogue: logits = sim*10; exclude diagonal exactly; capture target logit;
    // 16-lane shuffle reduce then one atomicAdd per (row, block).
    const int lhi = lane >> 4, llo = lane & 15;
    #pragma unroll
    for (int m = 0; m < 4; m++) {
        #pragma unroll
        for (int q = 0; q < 4; q++) {
            const int i  = brow + wm * 64 + m * 16 + lhi * 4 + q;
            const int tg = target[i];
            float psum = 0.0f;
            #pragma unroll
            for (int n = 0; n < 4; n++) {
                const int j = bcol + wn * 64 + n * 16 + llo;
                const float logit = acc[m][n][q] * TINV;
                if (j != i) psum += __expf(logit);
                if (j == tg) tlog[i] = logit;
            }
            psum += __shfl_xor(psum, 1);
            psum += __shfl_xor(psum, 2);
            psum += __shfl_xor(psum, 4);
            psum += __shfl_xor(psum, 8);
            if (llo == 0) atomicAdd(&rowsum[i], psum);
        }
    }
}

// Kernel 4: loss = mean_i( log(rowsum_i) - tlogit_i ), written as fp32 scalar.
__global__ __launch_bounds__(256) void kloss(const float* __restrict__ rowsum,
                                             const float* __restrict__ tlog,
                                             float* __restrict__ out) {
    __shared__ float red[256];
    float s = 0.0f;
    for (int i = threadIdx.x; i < NROW; i += 256)
        s += logf(rowsum[i]) - tlog[i];
    red[threadIdx.x] = s;
    __syncthreads();
    for (int k = 128; k > 0; k >>= 1) {
        if (threadIdx.x < k) red[threadIdx.x] += red[threadIdx.x + k];
        __syncthreads();
    }
    if (threadIdx.x == 0) out[0] = red[0] / (float)NROW;
}

extern "C" void kernel_launch(void* const* d_in, const int* in_sizes, int n_in,
                              void* d_out, int out_size, void* d_ws, size_t ws_size,
                              hipStream_t stream) {
    const float* feat  = (const float*)d_in[0];
    const int* labels  = (const int*)d_in[1];
    float* out = (float*)d_out;

    char* ws = (char*)d_ws;
    unsigned short* fb = (unsigned short*)ws;                       // 4096*512*2 = 4 MB
    float* rowsum = (float*)(ws + (size_t)NROW * DIM * 2);          // 16 KB
    float* tlog   = rowsum + NROW;                                  // 16 KB
    int*   target = (int*)(tlog + NROW);                            // 16 KB

    knorm  <<<NROW / 4, 256, 0, stream>>>(feat, fb);
    ktarget<<<1, 256, 0, stream>>>(labels, target, rowsum);
    ksim   <<<dim3(NROW / BN, NROW / BM), 256, 0, stream>>>(fb, target, rowsum, tlog);
    kloss  <<<1, 256, 0, stream>>>(rowsum, tlog, out);
}

// Round 3
// 63.692 us; speedup vs baseline: 1.1606x; 1.1606x over previous
//
#include <hip/hip_runtime.h>
#include <hip/hip_bf16.h>
#include <math.h>

#define NROW 4096
#define DIM  512
#define TINV 10.0f
#define EPSN 1e-8f
#define BM 128
#define BN 128
#define BK 64
#define NB  (NROW / BM)      // 32 row/col tiles
#define NBLK (NB * (NB + 1) / 2)  // 528 upper-triangle blocks

typedef __bf16 bf16x8 __attribute__((ext_vector_type(8)));
typedef float  f32x4  __attribute__((ext_vector_type(4)));

__device__ __forceinline__ void gload_lds16(const void* g, void* l) {
    __builtin_amdgcn_global_load_lds(
        (const __attribute__((address_space(1))) unsigned int*)g,
        (__attribute__((address_space(3))) unsigned int*)l,
        16, 0, 0);
}

// Kernel 1 (fused): blocks 0..1023 row-normalize fp32 -> bf16 (4 rows/block);
// block 1024 computes per-row targets and zeroes rowsum.
__global__ __launch_bounds__(256) void kprep(const float* __restrict__ feat,
                                             const int* __restrict__ labels,
                                             unsigned short* __restrict__ fb,
                                             int* __restrict__ target,
                                             float* __restrict__ rowsum) {
    if (blockIdx.x < NROW / 4) {
        const int row  = blockIdx.x * 4 + (threadIdx.x >> 6);
        const int lane = threadIdx.x & 63;
        const float* rp = feat + (size_t)row * DIM + lane * 8;
        float4 v0 = *(const float4*)rp;
        float4 v1 = *(const float4*)(rp + 4);
        float ss = v0.x*v0.x + v0.y*v0.y + v0.z*v0.z + v0.w*v0.w
                 + v1.x*v1.x + v1.y*v1.y + v1.z*v1.z + v1.w*v1.w;
        #pragma unroll
        for (int m = 1; m < 64; m <<= 1) ss += __shfl_xor(ss, m);
        const float inv = 1.0f / fmaxf(sqrtf(ss), EPSN);
        float vals[8] = {v0.x, v0.y, v0.z, v0.w, v1.x, v1.y, v1.z, v1.w};
        union { __hip_bfloat16 h[8]; int4 bits; } u;
        #pragma unroll
        for (int k = 0; k < 8; k++) u.h[k] = __float2bfloat16(vals[k] * inv);
        *(int4*)(fb + (size_t)row * DIM + lane * 8) = u.bits;
    } else {
        __shared__ int firstS[16], secondS[16];
        const int t = threadIdx.x;
        if (t < 16) { firstS[t] = NROW; secondS[t] = NROW; }
        for (int i = t; i < NROW; i += 256) rowsum[i] = 0.0f;
        __syncthreads();
        for (int i = t; i < NROW; i += 256) atomicMin(&firstS[labels[i]], i);
        __syncthreads();
        for (int i = t; i < NROW; i += 256) {
            const int c = labels[i];
            if (i != firstS[c]) atomicMin(&secondS[c], i);
        }
        __syncthreads();
        for (int i = t; i < NROW; i += 256) {
            const int c = labels[i];
            int tg = (firstS[c] == i) ? secondS[c] : firstS[c];
            if (tg >= NROW) tg = (i == 0) ? 1 : 0;  // no-positive: first dropped column
            target[i] = tg;
        }
    }
}

// Kernel 2: symmetric-half fused sim. Upper-triangle 128x128 tiles only.
// Double-buffered LDS (2-phase pipeline), XOR-swizzled via pre-swizzled
// global source (linear global_load_lds dest) + swizzled ds_read.
// Off-diagonal blocks contribute exp-sums in BOTH orientations.
__global__ __launch_bounds__(256) void ksim(const unsigned short* __restrict__ fb,
                                            const int* __restrict__ target,
                                            float* __restrict__ rowsum,
                                            float* __restrict__ tlog) {
    __shared__ __align__(16) unsigned short As[2][BM * BK];
    __shared__ __align__(16) unsigned short Bs[2][BM * BK];

    // triangular decode: bid -> (bi, bj), bi <= bj
    int bi = 0, rem = blockIdx.x;
    while (rem >= NB - bi) { rem -= NB - bi; bi++; }
    const int bj = bi + rem;
    const bool offdiag = (bi != bj);

    const int brow = bi * BM;
    const int bcol = bj * BN;
    const int tid  = threadIdx.x;
    const int wid  = tid >> 6;
    const int lane = tid & 63;
    const int wm = wid >> 1, wn = wid & 1;

    f32x4 acc[4][4];
    #pragma unroll
    for (int m = 0; m < 4; m++)
        #pragma unroll
        for (int n = 0; n < 4; n++)
            #pragma unroll
            for (int q = 0; q < 4; q++) acc[m][n][q] = 0.0f;

    const int r8  = lane >> 3;            // row within 8-row staging group
    const int c16 = lane & 7;             // 16B chunk within a 128B row
    const int sc  = c16 ^ r8;             // pre-swizzled source chunk (row&7 == r8)
    const int ro  = lane & 15;
    const int lg  = lane >> 4;
    const int rsw = ro & 7;               // read-side swizzle key

    // STAGE one K-tile (A rows from brow, B rows from bcol) into buffer `buf`.
    auto STAGE = [&](int buf, int kb) {
        const unsigned short* gA = fb + (size_t)(brow + wid * 32 + r8) * DIM + kb + sc * 8;
        const unsigned short* gB = fb + (size_t)(bcol + wid * 32 + r8) * DIM + kb + sc * 8;
        unsigned short* lA = &As[buf][(wid * 32) * BK];
        unsigned short* lB = &Bs[buf][(wid * 32) * BK];
        #pragma unroll
        for (int q = 0; q < 4; q++) {
            gload_lds16(gA + (size_t)q * 8 * DIM, lA + q * 8 * BK);
            gload_lds16(gB + (size_t)q * 8 * DIM, lB + q * 8 * BK);
        }
    };

    int cur = 0;
    STAGE(cur, 0);
    __syncthreads();

    for (int t = 0; t < DIM / BK; ++t) {
        if (t + 1 < DIM / BK) STAGE(cur ^ 1, (t + 1) * BK);
        const unsigned short* Ab = As[cur];
        const unsigned short* Bb = Bs[cur];
        #pragma unroll
        for (int kk = 0; kk < 2; kk++) {
            const int gc = kk * 4 + lg;            // global 16B-chunk index
            const int co = ((gc ^ rsw) * 8);       // swizzled LDS chunk offset (shorts)
            bf16x8 a[4], b[4];
            #pragma unroll
            for (int m = 0; m < 4; m++)
                a[m] = *(const bf16x8*)(Ab + (wm * 64 + m * 16 + ro) * BK + co);
            #pragma unroll
            for (int n = 0; n < 4; n++)
                b[n] = *(const bf16x8*)(Bb + (wn * 64 + n * 16 + ro) * BK + co);
            #pragma unroll
            for (int m = 0; m < 4; m++)
                #pragma unroll
                for (int n = 0; n < 4; n++)
                    acc[m][n] = __builtin_amdgcn_mfma_f32_16x16x32_bf16(a[m], b[n], acc[m][n], 0, 0, 0);
        }
        __syncthreads();   // drains this iter's STAGE (vmcnt) + protects buffer reuse
        cur ^= 1;
    }

    // Epilogue. C/D layout: col = lane&15 (llo), row = (lane>>4)*4 + q (lhi groups).
    const int lhi = lane >> 4, llo = lane & 15;
    float colacc[4] = {0.f, 0.f, 0.f, 0.f};
    int tgj[4];
    #pragma unroll
    for (int n = 0; n < 4; n++) tgj[n] = target[bcol + wn * 64 + n * 16 + llo];

    #pragma unroll
    for (int m = 0; m < 4; m++) {
        #pragma unroll
        for (int q = 0; q < 4; q++) {
            const int i  = brow + wm * 64 + m * 16 + lhi * 4 + q;
            const int tgi = target[i];
            float psum = 0.0f;
            #pragma unroll
            for (int n = 0; n < 4; n++) {
                const int j = bcol + wn * 64 + n * 16 + llo;
                const float logit = acc[m][n][q] * TINV;
                const float expv  = __expf(logit);
                if (j != i) psum += expv;             // diagonal excluded exactly
                if (j == tgi) tlog[i] = logit;
                if (offdiag) {
                    colacc[n] += expv;                // transposed-orientation sums
                    if (i == tgj[n]) tlog[j] = logit;
                }
            }
            psum += __shfl_xor(psum, 1);
            psum += __shfl_xor(psum, 2);
            psum += __shfl_xor(psum, 4);
            psum += __shfl_xor(psum, 8);
            if (llo == 0) atomicAdd(&rowsum[i], psum);
        }
    }
    if (offdiag) {
        #pragma unroll
        for (int n = 0; n < 4; n++) {
            colacc[n] += __shfl_xor(colacc[n], 16);
            colacc[n] += __shfl_xor(colacc[n], 32);
            if (lhi == 0) atomicAdd(&rowsum[bcol + wn * 64 + n * 16 + llo], colacc[n]);
        }
    }
}

// Kernel 3: loss = mean_i( log(rowsum_i) - tlogit_i ), fp32 scalar.
__global__ __launch_bounds__(256) void kloss(const float* __restrict__ rowsum,
                                             const float* __restrict__ tlog,
                                             float* __restrict__ out) {
    __shared__ float red[256];
    float s = 0.0f;
    for (int i = threadIdx.x; i < NROW; i += 256)
        s += logf(rowsum[i]) - tlog[i];
    red[threadIdx.x] = s;
    __syncthreads();
    for (int k = 128; k > 0; k >>= 1) {
        if (threadIdx.x < k) red[threadIdx.x] += red[threadIdx.x + k];
        __syncthreads();
    }
    if (threadIdx.x == 0) out[0] = red[0] / (float)NROW;
}

extern "C" void kernel_launch(void* const* d_in, const int* in_sizes, int n_in,
                              void* d_out, int out_size, void* d_ws, size_t ws_size,
                              hipStream_t stream) {
    const float* feat  = (const float*)d_in[0];
    const int* labels  = (const int*)d_in[1];
    float* out = (float*)d_out;

    char* ws = (char*)d_ws;
    unsigned short* fb = (unsigned short*)ws;                       // 4096*512*2 = 4 MB
    float* rowsum = (float*)(ws + (size_t)NROW * DIM * 2);          // 16 KB
    float* tlog   = rowsum + NROW;                                  // 16 KB
    int*   target = (int*)(tlog + NROW);                            // 16 KB

    kprep<<<NROW / 4 + 1, 256, 0, stream>>>(feat, labels, fb, target, rowsum);
    ksim <<<NBLK, 256, 0, stream>>>(fb, target, rowsum, tlog);
    kloss<<<1, 256, 0, stream>>>(rowsum, tlog, out);
}

// Round 4
// 43.365 us; speedup vs baseline: 1.7046x; 1.4687x over previous
//
#include <hip/hip_runtime.h>
#include <hip/hip_bf16.h>
#include <math.h>

#define NROW 4096
#define DIM  512
#define TINV8 0.0390625f   // 10/256: features scaled by 16 before fp8, sim scaled by 256
#define EPSN 1e-8f
#define BM 128
#define BK 64
#define NB  (NROW / BM)           // 32 tiles per side
#define NBLK (NB * (NB + 1) / 2)  // 528 upper-triangle blocks

typedef float f32x4 __attribute__((ext_vector_type(4)));

__device__ __forceinline__ void gload_lds16(const void* g, void* l) {
    __builtin_amdgcn_global_load_lds(
        (const __attribute__((address_space(1))) unsigned int*)g,
        (__attribute__((address_space(3))) unsigned int*)l,
        16, 0, 0);
}

// Kernel 1 (fused): blocks 0..1023 row-normalize fp32 -> fp8 e4m3 (x16 scale);
// block 1024 computes per-row targets and zeroes rowsum.
__global__ __launch_bounds__(256) void kprep(const float* __restrict__ feat,
                                             const int* __restrict__ labels,
                                             unsigned char* __restrict__ fb8,
                                             int* __restrict__ target,
                                             float* __restrict__ rowsum) {
    if (blockIdx.x < NROW / 4) {
        const int row  = blockIdx.x * 4 + (threadIdx.x >> 6);
        const int lane = threadIdx.x & 63;
        const float* rp = feat + (size_t)row * DIM + lane * 8;
        float4 v0 = *(const float4*)rp;
        float4 v1 = *(const float4*)(rp + 4);
        float ss = v0.x*v0.x + v0.y*v0.y + v0.z*v0.z + v0.w*v0.w
                 + v1.x*v1.x + v1.y*v1.y + v1.z*v1.z + v1.w*v1.w;
        #pragma unroll
        for (int m = 1; m < 64; m <<= 1) ss += __shfl_xor(ss, m);
        const float inv = 16.0f / fmaxf(sqrtf(ss), EPSN);
        int w0 = __builtin_amdgcn_cvt_pk_fp8_f32(v0.x * inv, v0.y * inv, 0, false);
        w0     = __builtin_amdgcn_cvt_pk_fp8_f32(v0.z * inv, v0.w * inv, w0, true);
        int w1 = __builtin_amdgcn_cvt_pk_fp8_f32(v1.x * inv, v1.y * inv, 0, false);
        w1     = __builtin_amdgcn_cvt_pk_fp8_f32(v1.z * inv, v1.w * inv, w1, true);
        *(int2*)(fb8 + (size_t)row * DIM + lane * 8) = make_int2(w0, w1);
    } else {
        __shared__ int firstS[16], secondS[16];
        const int t = threadIdx.x;
        if (t < 16) { firstS[t] = NROW; secondS[t] = NROW; }
        for (int i = t; i < NROW; i += 256) rowsum[i] = 0.0f;
        __syncthreads();
        for (int i = t; i < NROW; i += 256) atomicMin(&firstS[labels[i]], i);
        __syncthreads();
        for (int i = t; i < NROW; i += 256) {
            const int c = labels[i];
            if (i != firstS[c]) atomicMin(&secondS[c], i);
        }
        __syncthreads();
        for (int i = t; i < NROW; i += 256) {
            const int c = labels[i];
            int tg = (firstS[c] == i) ? secondS[c] : firstS[c];
            if (tg >= NROW) tg = (i == 0) ? 1 : 0;  // no-positive: first dropped column
            target[i] = tg;
        }
    }
}

// Kernel 2: symmetric-half fused sim, fp8 e4m3 MFMA. Upper-triangle 128x128
// tiles. Double-buffered 32 KB LDS -> 5 blocks/CU, all 528 blocks resident.
// XOR-swizzle key (r&3)^((r>>2)&3) applied to pre-swizzled global source
// (linear global_load_lds dest) and to the ds_read_b64 chunk offset.
__global__ __launch_bounds__(256) void ksim(const unsigned char* __restrict__ fb8,
                                            const int* __restrict__ target,
                                            float* __restrict__ rowsum,
                                            float* __restrict__ tlog) {
    __shared__ __align__(16) unsigned char As[2][BM * BK];  // 8 KB per buffer
    __shared__ __align__(16) unsigned char Bs[2][BM * BK];

    // triangular decode: bid -> (bi, bj), bi <= bj
    int bi = 0, rem = blockIdx.x;
    while (rem >= NB - bi) { rem -= NB - bi; bi++; }
    const int bj = bi + rem;
    const bool offdiag = (bi != bj);

    const int brow = bi * BM;
    const int bcol = bj * BM;
    const int tid  = threadIdx.x;
    const int wid  = tid >> 6;
    const int lane = tid & 63;
    const int wm = wid >> 1, wn = wid & 1;

    f32x4 acc[4][4];
    #pragma unroll
    for (int m = 0; m < 4; m++)
        #pragma unroll
        for (int n = 0; n < 4; n++)
            #pragma unroll
            for (int q = 0; q < 4; q++) acc[m][n][q] = 0.0f;

    // Staging lane map: 16 rows per gload; lane l -> row l>>2, 16B-pos l&3.
    const int skey = ((lane >> 2) & 3) ^ ((lane >> 4) & 3);  // (r&3)^((r>>2)&3)
    const int sc   = (lane & 3) ^ skey;                      // pre-swizzled src chunk

    auto STAGE = [&](int buf, int kb) {
        #pragma unroll
        for (int q = 0; q < 2; q++) {
            const int r0 = wid * 32 + q * 16;
            const unsigned char* gA = fb8 + (size_t)(brow + r0 + (lane >> 2)) * DIM + kb + sc * 16;
            const unsigned char* gB = fb8 + (size_t)(bcol + r0 + (lane >> 2)) * DIM + kb + sc * 16;
            gload_lds16(gA, &As[buf][r0 * BK]);
            gload_lds16(gB, &Bs[buf][r0 * BK]);
        }
    };

    const int ro   = lane & 15;
    const int rkey = (ro & 3) ^ ((ro >> 2) & 3);
    const int hp   = (lane >> 4) & 1;   // 8B half within 16B chunk
    const int g2   = lane >> 5;         // chunk LSB from k-octet

    int cur = 0;
    STAGE(cur, 0);
    __syncthreads();

    for (int t = 0; t < DIM / BK; ++t) {
        if (t + 1 < DIM / BK) STAGE(cur ^ 1, (t + 1) * BK);
        const unsigned char* Ab = As[cur];
        const unsigned char* Bb = Bs[cur];
        #pragma unroll
        for (int kk = 0; kk < 2; kk++) {
            const int p   = (kk * 2 + g2) ^ rkey;   // swizzled 16B chunk
            const int cof = (p * 2 + hp) * 8;       // byte offset within 64B row
            long a[4], b[4];
            #pragma unroll
            for (int m = 0; m < 4; m++)
                a[m] = *(const long*)(Ab + (wm * 64 + m * 16 + ro) * BK + cof);
            #pragma unroll
            for (int n = 0; n < 4; n++)
                b[n] = *(const long*)(Bb + (wn * 64 + n * 16 + ro) * BK + cof);
            #pragma unroll
            for (int m = 0; m < 4; m++)
                #pragma unroll
                for (int n = 0; n < 4; n++)
                    acc[m][n] = __builtin_amdgcn_mfma_f32_16x16x32_fp8_fp8(a[m], b[n], acc[m][n], 0, 0, 0);
        }
        __syncthreads();   // drains this iter's STAGE + protects buffer reuse
        cur ^= 1;
    }

    // Epilogue. C/D layout: col = lane&15, row = (lane>>4)*4 + q.
    const int lhi = lane >> 4, llo = lane & 15;
    float colacc[4] = {0.f, 0.f, 0.f, 0.f};
    int tgj[4];
    #pragma unroll
    for (int n = 0; n < 4; n++) tgj[n] = target[bcol + wn * 64 + n * 16 + llo];

    #pragma unroll
    for (int m = 0; m < 4; m++) {
        #pragma unroll
        for (int q = 0; q < 4; q++) {
            const int i  = brow + wm * 64 + m * 16 + lhi * 4 + q;
            const int tgi = target[i];
            float psum = 0.0f;
            #pragma unroll
            for (int n = 0; n < 4; n++) {
                const int j = bcol + wn * 64 + n * 16 + llo;
                const float logit = acc[m][n][q] * TINV8;
                const float expv  = __expf(logit);
                if (j != i) psum += expv;             // diagonal excluded exactly
                if (j == tgi) tlog[i] = logit;
                if (offdiag) {
                    colacc[n] += expv;                // transposed-orientation sums
                    if (i == tgj[n]) tlog[j] = logit;
                }
            }
            psum += __shfl_xor(psum, 1);
            psum += __shfl_xor(psum, 2);
            psum += __shfl_xor(psum, 4);
            psum += __shfl_xor(psum, 8);
            if (llo == 0) atomicAdd(&rowsum[i], psum);
        }
    }
    if (offdiag) {
        #pragma unroll
        for (int n = 0; n < 4; n++) {
            colacc[n] += __shfl_xor(colacc[n], 16);
            colacc[n] += __shfl_xor(colacc[n], 32);
            if (lhi == 0) atomicAdd(&rowsum[bcol + wn * 64 + n * 16 + llo], colacc[n]);
        }
    }
}

// Kernel 3: loss = mean_i( log(rowsum_i) - tlogit_i ), fp32 scalar.
__global__ __launch_bounds__(256) void kloss(const float* __restrict__ rowsum,
                                             const float* __restrict__ tlog,
                                             float* __restrict__ out) {
    __shared__ float red[256];
    float s = 0.0f;
    for (int i = threadIdx.x; i < NROW; i += 256)
        s += logf(rowsum[i]) - tlog[i];
    red[threadIdx.x] = s;
    __syncthreads();
    for (int k = 128; k > 0; k >>= 1) {
        if (threadIdx.x < k) red[threadIdx.x] += red[threadIdx.x + k];
        __syncthreads();
    }
    if (threadIdx.x == 0) out[0] = red[0] / (float)NROW;
}

extern "C" void kernel_launch(void* const* d_in, const int* in_sizes, int n_in,
                              void* d_out, int out_size, void* d_ws, size_t ws_size,
                              hipStream_t stream) {
    const float* feat  = (const float*)d_in[0];
    const int* labels  = (const int*)d_in[1];
    float* out = (float*)d_out;

    char* ws = (char*)d_ws;
    unsigned char* fb8 = (unsigned char*)ws;                 // 4096*512 = 2 MB
    float* rowsum = (float*)(ws + (size_t)NROW * DIM);       // 16 KB
    float* tlog   = rowsum + NROW;                           // 16 KB
    int*   target = (int*)(tlog + NROW);                     // 16 KB

    kprep<<<NROW / 4 + 1, 256, 0, stream>>>(feat, labels, fb8, target, rowsum);
    ksim <<<NBLK, 256, 0, stream>>>(fb8, target, rowsum, tlog);
    kloss<<<1, 256, 0, stream>>>(rowsum, tlog, out);
}